// Round 7
// baseline (102.945 us; speedup 1.0000x reference)
//
#include <hip/hip_runtime.h>

// MultiGaussSpatialConv: B=1, N=M=8192, D=3, C=16, fp32.
// out[n,c] = sum_i w_i * (sum_m e_i(n,m) yf[m,c]) / (sum_m e_i(n,m))
// e_i = exp(-d2/(2 s^2)), 1/(2 s^2) = {200, 50, 12.5} -> e0 = e2^16, e1 = e2^4.
//
// R7 (= R6 with __exp2f -> __builtin_amdgcn_exp2f; glibc macro collision):
//  (a) 4-way m-split -> grid 2048, 8 blocks/CU; plain-store partials +
//      small reduce kernel (kernel-boundary coherence; NOT R4's atomics).
//  (b) constant-folded exp2 form: prep bakes q=(25*log2e*y, -12.5*log2e*|y|^2);
//      inner loop: 3 fma + v_exp_f32 + 5 mul per pair-slot; E2x hoisted
//      per-lane (keeps e2<=1 so the e2^4/e2^16 chain cannot overflow).

static constexpr int Nn = 8192;
static constexpr int Mm = 8192;
static constexpr float KC = 36.0673761f;    // 25 * log2(e)
static constexpr float KD = -18.0336880f;   // -12.5 * log2(e)

typedef _Float16 half8 __attribute__((ext_vector_type(8)));
typedef __fp16  fp16x2 __attribute__((ext_vector_type(2)));
typedef float  float4v __attribute__((ext_vector_type(4)));

#define MFMA_F16 __builtin_amdgcn_mfma_f32_16x16x32_f16
#define EXP2F(v) __builtin_amdgcn_exp2f(v)

// ---------------- prep: q[m] quad (constant-folded) + yf -> fp16 B-fragments
// frag idx(m,c) = (m>>5)*512 + (((m&31)>>3)*16 + c)*8 + (m&7)
__global__ __launch_bounds__(256) void mgsc_prep(
    const float* __restrict__ y, const float* __restrict__ yf,
    float4* __restrict__ q, _Float16* __restrict__ frag)
{
    const int t = blockIdx.x * 256 + threadIdx.x;   // 0 .. Mm*16-1
    const int m = t >> 4, c = t & 15;
    const int idx = ((m >> 5) << 9) + ((((m & 31) >> 3) << 4) + c) * 8 + (m & 7);
    frag[idx] = (_Float16)yf[t];                    // RNE
    if (t < Mm) {
        const float ax = y[3 * t], ay = y[3 * t + 1], az = y[3 * t + 2];
        q[t] = make_float4(KC * ax, KC * ay, KC * az,
                           KD * (ax * ax + ay * ay + az * az));
    }
}

// ---------------- main: grid (512 n-tiles, 4 m-chunks); 4 waves/block
__global__ __launch_bounds__(256) void mgsc_main(
    const float* __restrict__ x, const float4* __restrict__ q,
    const _Float16* __restrict__ frag, float* __restrict__ part)
{
    __shared__ float redS[3 * 64 * 25];             // stride 25: conflict-free

    const int tid  = threadIdx.x;
    const int wave = tid >> 6, lane = tid & 63;
    const int g    = lane >> 4, c = lane & 15;
    const int xb   = blockIdx.x, yb = blockIdx.y;
    const int n0   = xb * 16;
    const int nrow = n0 + c;                        // A-frag row for this lane

    const float xx = x[3 * nrow], xy = x[3 * nrow + 1], xz = x[3 * nrow + 2];
    const float E2x = EXP2F(KD * __fmaf_rn(xx, xx, __fmaf_rn(xy, xy, xz * xz)));

    float4v acc0 = {0.f, 0.f, 0.f, 0.f}, acc1 = acc0, acc2 = acc0;
    float4v dac0 = acc0, dac1 = acc0, dac2 = acc0;

    const _Float16 onev = (c == 0) ? (_Float16)1.0f : (_Float16)0.0f;
    half8 bone = {onev, onev, onev, onev, onev, onev, onev, onev};

    const int kt0 = yb * 64 + wave * 16;            // 256 kt total; 16/wave
    for (int kt = kt0; kt < kt0 + 16; ++kt) {
        const float4* qk = q + (kt << 5) + (g << 3);
        float E0[8], E1[8], E2[8];
#pragma unroll
        for (int j = 0; j < 8; ++j) {
            const float4 Q = qk[j];                 // L1/L2-hot, 4 addrs/wave
            const float arg = __fmaf_rn(xx, Q.x, __fmaf_rn(xy, Q.y, __fmaf_rn(xz, Q.z, Q.w)));
            const float e2 = E2x * EXP2F(arg);      // sigma 0.2, e2 <= ~1
            const float t2 = e2 * e2;
            const float e1 = t2 * t2;               // sigma 0.1  (e2^4)
            const float u2 = e1 * e1;
            const float e0 = u2 * u2;               // sigma 0.05 (e2^16)
            E0[j] = e0; E1[j] = e1; E2[j] = e2;
        }
        union { fp16x2 h2[4]; half8 v; } A0, A1, A2;
#pragma unroll
        for (int jj = 0; jj < 4; ++jj) {
            A0.h2[jj] = __builtin_amdgcn_cvt_pkrtz(E0[2 * jj], E0[2 * jj + 1]);
            A1.h2[jj] = __builtin_amdgcn_cvt_pkrtz(E1[2 * jj], E1[2 * jj + 1]);
            A2.h2[jj] = __builtin_amdgcn_cvt_pkrtz(E2[2 * jj], E2[2 * jj + 1]);
        }
        const half8 B = *reinterpret_cast<const half8*>(frag + ((size_t)kt << 9) + (lane << 3));
        acc0 = MFMA_F16(A0.v, B, acc0, 0, 0, 0);
        acc1 = MFMA_F16(A1.v, B, acc1, 0, 0, 0);
        acc2 = MFMA_F16(A2.v, B, acc2, 0, 0, 0);
        dac0 = MFMA_F16(A0.v, bone, dac0, 0, 0, 0);
        dac1 = MFMA_F16(A1.v, bone, dac1, 0, 0, 0);
        dac2 = MFMA_F16(A2.v, bone, dac2, 0, 0, 0);
    }

    // ---- cross-wave reduction via LDS (waves 1-3 stash, wave 0 sums)
    if (wave != 0) {
        float* s = redS + (wave - 1) * 64 * 25 + lane * 25;
#pragma unroll
        for (int r = 0; r < 4; ++r) {
            s[r]      = acc0[r];
            s[4 + r]  = acc1[r];
            s[8 + r]  = acc2[r];
            s[12 + r] = dac0[r];
            s[16 + r] = dac1[r];
            s[20 + r] = dac2[r];
        }
    }
    __syncthreads();
    if (wave != 0) return;

#pragma unroll
    for (int ww = 0; ww < 3; ++ww) {
        const float* s = redS + ww * 64 * 25 + lane * 25;
#pragma unroll
        for (int r = 0; r < 4; ++r) {
            acc0[r] += s[r];
            acc1[r] += s[4 + r];
            acc2[r] += s[8 + r];
            dac0[r] += s[12 + r];
            dac1[r] += s[16 + r];
            dac2[r] += s[20 + r];
        }
    }

    // ---- write partials: part[yb][n][52], coalesced-ish plain stores
    float* pb = part + ((size_t)yb * Nn) * 52;
#pragma unroll
    for (int r = 0; r < 4; ++r) {
        const int n = n0 + (g << 2) + r;            // C/D: col=c, row=g*4+r
        float* row = pb + (size_t)n * 52;
        row[c]      = acc0[r];
        row[16 + c] = acc1[r];
        row[32 + c] = acc2[r];
        if (c == 0) {
            row[48] = dac0[r];
            row[49] = dac1[r];
            row[50] = dac2[r];
        }
    }
}

// ---------------- reduce: thread (n,c) sums 4 chunks, finalizes
__global__ __launch_bounds__(256) void mgsc_reduce(
    const float* __restrict__ part, float* __restrict__ out)
{
    const int t = blockIdx.x * 256 + threadIdx.x;   // 0 .. Nn*16-1
    const int n = t >> 4, c = t & 15;
    float s0 = 0.f, s1 = 0.f, s2 = 0.f, d0 = 0.f, d1 = 0.f, d2 = 0.f;
#pragma unroll
    for (int k = 0; k < 4; ++k) {
        const float* row = part + ((size_t)k * Nn + n) * 52;
        s0 += row[c];
        s1 += row[16 + c];
        s2 += row[32 + c];
        d0 += row[48];
        d1 += row[49];
        d2 += row[50];
    }
    out[(size_t)n * 16 + c] = 0.3f * s0 / d0 + 0.3f * s1 / d1 + 0.4f * s2 / d2;
}

// ---------------- fused VALU fallback (workspace too small)
__global__ __launch_bounds__(256) void mgsc_fused(
    const float* __restrict__ x, const float* __restrict__ y,
    const float* __restrict__ yf, float* __restrict__ out)
{
    __shared__ float yS[256 * 3];
    __shared__ float yfS[256 * 16];
    const int tid = threadIdx.x;
    const int n   = blockIdx.x * 256 + tid;
    const float xx = x[3 * n], xy = x[3 * n + 1], xz = x[3 * n + 2];
    float a0[16], a1[16], a2[16];
#pragma unroll
    for (int c = 0; c < 16; ++c) { a0[c] = 0.f; a1[c] = 0.f; a2[c] = 0.f; }
    float den0 = 0.f, den1 = 0.f, den2 = 0.f;
    for (int mt = 0; mt < Mm; mt += 256) {
        const float4* ysrc = reinterpret_cast<const float4*>(y + (size_t)mt * 3);
        if (tid < 192) reinterpret_cast<float4*>(yS)[tid] = ysrc[tid];
        const float4* fsrc = reinterpret_cast<const float4*>(yf + (size_t)mt * 16);
#pragma unroll
        for (int k = 0; k < 4; ++k)
            reinterpret_cast<float4*>(yfS)[tid + 256 * k] = fsrc[tid + 256 * k];
        __syncthreads();
        for (int mm = 0; mm < 256; ++mm) {
            const float dx = xx - yS[3 * mm], dy = xy - yS[3 * mm + 1], dz = xz - yS[3 * mm + 2];
            const float d2 = dx * dx + dy * dy + dz * dz;
            const float e2 = __expf(-12.5f * d2);
            const float t = e2 * e2, e1 = t * t, u = e1 * e1, e0 = u * u;
            den0 += e0; den1 += e1; den2 += e2;
            const float4* fr = reinterpret_cast<const float4*>(yfS + mm * 16);
#pragma unroll
            for (int k = 0; k < 4; ++k) {
                const float4 f = fr[k];
                a0[4*k+0] += e0 * f.x; a0[4*k+1] += e0 * f.y; a0[4*k+2] += e0 * f.z; a0[4*k+3] += e0 * f.w;
                a1[4*k+0] += e1 * f.x; a1[4*k+1] += e1 * f.y; a1[4*k+2] += e1 * f.z; a1[4*k+3] += e1 * f.w;
                a2[4*k+0] += e2 * f.x; a2[4*k+1] += e2 * f.y; a2[4*k+2] += e2 * f.z; a2[4*k+3] += e2 * f.w;
            }
        }
        __syncthreads();
    }
    const float r0 = 0.3f / den0, r1 = 0.3f / den1, r2 = 0.4f / den2;
#pragma unroll
    for (int c = 0; c < 16; ++c)
        out[(size_t)n * 16 + c] = a0[c] * r0 + a1[c] * r1 + a2[c] * r2;
}

extern "C" void kernel_launch(void* const* d_in, const int* in_sizes, int n_in,
                              void* d_out, int out_size, void* d_ws, size_t ws_size,
                              hipStream_t stream) {
    const float* x  = (const float*)d_in[0];
    const float* y  = (const float*)d_in[1];
    const float* yf = (const float*)d_in[2];
    float* out = (float*)d_out;

    const size_t qB    = (size_t)Mm * sizeof(float4);            // 128 KB
    const size_t fragB = (size_t)Mm * 16 * sizeof(_Float16);     // 256 KB
    const size_t partB = (size_t)4 * Nn * 52 * sizeof(float);    // 6.8 MB
    if (qB + fragB + partB > ws_size) {
        mgsc_fused<<<Nn / 256, 256, 0, stream>>>(x, y, yf, out);
        return;
    }
    float4*   q    = (float4*)d_ws;
    _Float16* frag = (_Float16*)((char*)d_ws + qB);
    float*    part = (float*)((char*)d_ws + qB + fragB);

    mgsc_prep<<<(Mm * 16) / 256, 256, 0, stream>>>(y, yf, q, frag);
    mgsc_main<<<dim3(Nn / 16, 4), 256, 0, stream>>>(x, q, frag, part);
    mgsc_reduce<<<(Nn * 16) / 256, 256, 0, stream>>>(part, out);
}